// Round 1
// 1542.064 us; speedup vs baseline: 1.7011x; 1.7011x over previous
//
#include <hip/hip_runtime.h>
#include <math.h>

// LGMLoss pipeline, v2: bf16 split-precision MFMA GEMM for dist.
// dist = A @ W^T + sumc, A[b] = [f^2 | f] (K=256), W[c] = [inv | -2*mu*inv].
// A = Ah+Al, W = Wh+Wl (bf16 hi/lo RNE split); dist ~= Ah*Wh + Al*Wh + Ah*Wl.
// Per-product rel err ~2^-17 -> dist abs err ~2e-4 (values ~256): fp32-safe.
// k2 writes dist (into out_logits buffer); k3 re-reads rows for lse/lse_m/cd;
// k4 finalizes logits+margin in-place; k5 scalars.

#define ALPHA_F 0.1f
typedef unsigned short u16;
typedef unsigned int u32;

using bf16x8 = __attribute__((ext_vector_type(8))) short;  // 8 bf16 (4 VGPRs)
using f32x4  = __attribute__((ext_vector_type(4))) float;  // 4 fp32 acc

__device__ __forceinline__ u16 bf16_rne(float x) {
    u32 u = __float_as_uint(x);
    u32 r = u + 0x7FFFu + ((u >> 16) & 1u);
    return (u16)(r >> 16);
}
__device__ __forceinline__ void bf16_split(float x, u16& h, u16& lo) {
    u16 hh = bf16_rne(x);
    float hf = __uint_as_float(((u32)hh) << 16);
    h = hh;
    lo = bf16_rne(x - hf);
}

// direct-to-LDS 16B async copy: LDS dest = wave-uniform base + lane*16
__device__ __forceinline__ void gll16(const u16* g, u16* s) {
    __builtin_amdgcn_global_load_lds(
        (const __attribute__((address_space(1))) void*)g,
        (__attribute__((address_space(3))) void*)s, 16, 0, 0);
}

// ---------------- k0: feat -> Ah/Al [B][256] ----------------
__global__ __launch_bounds__(256) void k0_featprep(
    const float* __restrict__ feat, u16* __restrict__ Ah, u16* __restrict__ Al, int BD)
{
    int i = blockIdx.x * 256 + threadIdx.x;
    if (i >= BD) return;
    int b = i >> 7, d = i & 127;
    float f = feat[i];
    size_t base = (size_t)b * 256;
    u16 h, lo;
    bf16_split(f * f, h, lo);
    Ah[base + d] = h; Al[base + d] = lo;
    bf16_split(f, h, lo);
    Ah[base + 128 + d] = h; Al[base + 128 + d] = lo;
}

// ---------------- k1: centers/log_covs -> Wh/Wl [C][256], sumc, slog ----------------
__global__ __launch_bounds__(256) void k1_classprep(
    const float* __restrict__ centers, const float* __restrict__ log_covs,
    u16* __restrict__ Wh, u16* __restrict__ Wl,
    float* __restrict__ sumc, float* __restrict__ slog)
{
    int tid = threadIdx.x;
    int c = blockIdx.x * 4 + (tid >> 6);   // 4 classes per block, 64 lanes each
    int l = tid & 63;
    float2 mu = *(const float2*)(centers  + (size_t)c * 128 + l * 2);
    float2 lc = *(const float2*)(log_covs + (size_t)c * 128 + l * 2);
    float i0 = expf(-lc.x), i1 = expf(-lc.y);
    size_t base = (size_t)c * 256 + l * 2;
    u16 h0, l0, h1, l1;
    bf16_split(i0, h0, l0); bf16_split(i1, h1, l1);
    *(u32*)(Wh + base) = (u32)h0 | ((u32)h1 << 16);
    *(u32*)(Wl + base) = (u32)l0 | ((u32)l1 << 16);
    bf16_split(-2.f * mu.x * i0, h0, l0); bf16_split(-2.f * mu.y * i1, h1, l1);
    *(u32*)(Wh + base + 128) = (u32)h0 | ((u32)h1 << 16);
    *(u32*)(Wl + base + 128) = (u32)l0 | ((u32)l1 << 16);
    float ps = fmaf(mu.x * mu.x, i0, mu.y * mu.y * i1);
    float pl = lc.x + lc.y;
    #pragma unroll
    for (int off = 32; off; off >>= 1) {
        ps += __shfl_xor(ps, off);
        pl += __shfl_xor(pl, off);
    }
    if (l == 0) { sumc[c] = ps; slog[c] = pl; }
}

// ---------------- k2: MFMA dist GEMM ----------------
// 128x128 tile, BK=64, 4 waves (2x2), each wave 64x64 = 4x4 frags of 16x16.
// 3-term split accumulate: AhWh + AlWh + AhWl.
__global__ __launch_bounds__(256) void k2_mfma(
    const u16* __restrict__ Ahg, const u16* __restrict__ Alg,
    const u16* __restrict__ Whg, const u16* __restrict__ Wlg,
    const float* __restrict__ sumc, float* __restrict__ dist_out, int C)
{
    __shared__ u16 sAh[128 * 64];   // 16 KB each, 64 KB total
    __shared__ u16 sAl[128 * 64];
    __shared__ u16 sWh[128 * 64];
    __shared__ u16 sWl[128 * 64];

    const int tid = threadIdx.x;
    const int w = tid >> 6, l = tid & 63;
    const int wr = w >> 1, wcv = w & 1;
    const int c0 = blockIdx.x * 128;
    const int row0 = blockIdx.y * 128;

    // staging coords: lane covers 16B = 8 bf16; 8 lanes per 64-col row
    const int sr = (w << 3) + (l >> 3);     // row within 32-row chunk
    const int sc8 = (l & 7) * 8;            // k element offset

    auto stage4 = [&](const u16* __restrict__ g, u16* s, int base, int kk0) {
        const u16* gp = g + (size_t)(base + sr) * 256 + kk0 + sc8;
        u16* sp = s + (w << 9);             // wave-uniform LDS base (+lane*16 by HW)
        #pragma unroll
        for (int it = 0; it < 4; ++it)
            gll16(gp + it * 32 * 256, sp + it * 2048);
    };

    f32x4 acc[4][4] = {};

    for (int kt = 0; kt < 4; ++kt) {
        const int kk0 = kt * 64;
        if (kt) __syncthreads();            // prior reads done before overwrite
        stage4(Ahg, sAh, row0, kk0);
        stage4(Alg, sAl, row0, kk0);
        stage4(Whg, sWh, c0, kk0);
        stage4(Wlg, sWl, c0, kk0);
        asm volatile("s_waitcnt vmcnt(0)");
        __syncthreads();

        #pragma unroll
        for (int ks = 0; ks < 2; ++ks) {
            const int ko = ks * 32 + (l >> 4) * 8;
            bf16x8 ah[4], al[4], wh[4], wl[4];
            #pragma unroll
            for (int m = 0; m < 4; ++m) {
                int rowA = wr * 64 + m * 16 + (l & 15);
                ah[m] = *(const bf16x8*)(sAh + rowA * 64 + ko);
                al[m] = *(const bf16x8*)(sAl + rowA * 64 + ko);
            }
            #pragma unroll
            for (int n = 0; n < 4; ++n) {
                int rowW = wcv * 64 + n * 16 + (l & 15);
                wh[n] = *(const bf16x8*)(sWh + rowW * 64 + ko);
                wl[n] = *(const bf16x8*)(sWl + rowW * 64 + ko);
            }
            #pragma unroll
            for (int m = 0; m < 4; ++m)
                #pragma unroll
                for (int n = 0; n < 4; ++n) {
                    acc[m][n] = __builtin_amdgcn_mfma_f32_16x16x32_bf16(ah[m], wh[n], acc[m][n], 0, 0, 0);
                    acc[m][n] = __builtin_amdgcn_mfma_f32_16x16x32_bf16(al[m], wh[n], acc[m][n], 0, 0, 0);
                    acc[m][n] = __builtin_amdgcn_mfma_f32_16x16x32_bf16(ah[m], wl[n], acc[m][n], 0, 0, 0);
                }
        }
    }

    // epilogue: C/D layout col=lane&15, row=(lane>>4)*4+reg  [m89-verified]
    const int rbase = row0 + wr * 64 + (l >> 4) * 4;
    const int cbase = c0 + wcv * 64 + (l & 15);
    float scv[4];
    #pragma unroll
    for (int n = 0; n < 4; ++n) scv[n] = sumc[cbase + n * 16];
    #pragma unroll
    for (int m = 0; m < 4; ++m)
        #pragma unroll
        for (int r = 0; r < 4; ++r) {
            size_t rowoff = (size_t)(rbase + m * 16 + r) * C;
            #pragma unroll
            for (int n = 0; n < 4; ++n)
                dist_out[rowoff + cbase + n * 16] = acc[m][n][r] + scv[n];
        }
}

// ---------------- k3: per-row lse / lse_m / cd / det ----------------
__global__ __launch_bounds__(256) void k3_lse(
    const float* __restrict__ dist, const float* __restrict__ slog,
    const float* __restrict__ feat, const float* __restrict__ centers,
    const int* __restrict__ label,
    float* __restrict__ lse, float* __restrict__ lse_m,
    float* __restrict__ rowcd, float* __restrict__ rowdet, int C)
{
    const int b = blockIdx.x, tid = threadIdx.x;
    const int lab = label[b];
    const float* drow = dist + (size_t)b * C;
    float mA = -INFINITY, sA = 0.f, mB = -INFINITY, sB = 0.f;
    for (int c = tid * 4; c < C; c += 1024) {
        float4 dv = *(const float4*)(drow + c);
        float4 sl = *(const float4*)(slog + c);
        float x0 = -0.5f * (sl.x + dv.x);
        float x1 = -0.5f * (sl.y + dv.y);
        float x2 = -0.5f * (sl.z + dv.z);
        float x3 = -0.5f * (sl.w + dv.w);
        float m0 = (c + 0 == lab) ? (1.f + ALPHA_F) : 1.f;
        float m1 = (c + 1 == lab) ? (1.f + ALPHA_F) : 1.f;
        float m2 = (c + 2 == lab) ? (1.f + ALPHA_F) : 1.f;
        float m3 = (c + 3 == lab) ? (1.f + ALPHA_F) : 1.f;
        float y0 = -0.5f * (sl.x + dv.x * m0);
        float y1 = -0.5f * (sl.y + dv.y * m1);
        float y2 = -0.5f * (sl.z + dv.z * m2);
        float y3 = -0.5f * (sl.w + dv.w * m3);
        float xm = fmaxf(fmaxf(x0, x1), fmaxf(x2, x3));
        float xs = __expf(x0 - xm) + __expf(x1 - xm) + __expf(x2 - xm) + __expf(x3 - xm);
        if (xm > mA) { sA = sA * __expf(mA - xm) + xs; mA = xm; }
        else sA += xs * __expf(xm - mA);
        float ym = fmaxf(fmaxf(y0, y1), fmaxf(y2, y3));
        float ys = __expf(y0 - ym) + __expf(y1 - ym) + __expf(y2 - ym) + __expf(y3 - ym);
        if (ym > mB) { sB = sB * __expf(mB - ym) + ys; mB = ym; }
        else sB += ys * __expf(ym - mB);
    }
    float cd = 0.f;
    if (tid < 128) {
        float df = feat[(size_t)b * 128 + tid] - centers[(size_t)lab * 128 + tid];
        cd = df * df;
    }
    #pragma unroll
    for (int off = 32; off; off >>= 1) {
        float om = __shfl_xor(mA, off), os = __shfl_xor(sA, off);
        float M = fmaxf(mA, om);
        sA = sA * __expf(mA - M) + os * __expf(om - M); mA = M;
        om = __shfl_xor(mB, off); os = __shfl_xor(sB, off);
        M = fmaxf(mB, om);
        sB = sB * __expf(mB - M) + os * __expf(om - M); mB = M;
        cd += __shfl_xor(cd, off);
    }
    __shared__ float red[4][5];
    int w = tid >> 6;
    if ((tid & 63) == 0) {
        red[w][0] = mA; red[w][1] = sA; red[w][2] = mB; red[w][3] = sB; red[w][4] = cd;
    }
    __syncthreads();
    if (tid == 0) {
        mA = red[0][0]; sA = red[0][1]; mB = red[0][2]; sB = red[0][3]; cd = red[0][4];
        #pragma unroll
        for (int i = 1; i < 4; ++i) {
            float M = fmaxf(mA, red[i][0]);
            sA = sA * __expf(mA - M) + red[i][1] * __expf(red[i][0] - M); mA = M;
            M = fmaxf(mB, red[i][2]);
            sB = sB * __expf(mB - M) + red[i][3] * __expf(red[i][2] - M); mB = M;
            cd += red[i][4];
        }
        lse[b] = mA + logf(sA);
        lse_m[b] = mB + logf(sB);
        rowcd[b] = cd;
        rowdet[b] = slog[lab];
    }
}

// ---------------- k4: final elementwise logits/margin ----------------
__global__ __launch_bounds__(256) void k4_final(
    float* __restrict__ out_logits, float* __restrict__ out_margin,
    const float* __restrict__ slog, const int* __restrict__ label,
    const float* __restrict__ lse, const float* __restrict__ lse_m, int C)
{
    int b = blockIdx.y;
    int c = (blockIdx.x * 256 + threadIdx.x) * 4;
    if (c >= C) return;
    size_t idx = (size_t)b * C + c;
    float4 dv = *(const float4*)(out_logits + idx);
    float4 sl = *(const float4*)(slog + c);
    float L = lse[b], Lm = lse_m[b];
    int lab = label[b];
    float4 lg, mg;
    float m0 = (c + 0 == lab) ? (1.f + ALPHA_F) : 1.f;
    float m1 = (c + 1 == lab) ? (1.f + ALPHA_F) : 1.f;
    float m2 = (c + 2 == lab) ? (1.f + ALPHA_F) : 1.f;
    float m3 = (c + 3 == lab) ? (1.f + ALPHA_F) : 1.f;
    lg.x = -0.5f * (sl.x + dv.x) - L;
    lg.y = -0.5f * (sl.y + dv.y) - L;
    lg.z = -0.5f * (sl.z + dv.z) - L;
    lg.w = -0.5f * (sl.w + dv.w) - L;
    mg.x = -0.5f * (sl.x + dv.x * m0) - Lm;
    mg.y = -0.5f * (sl.y + dv.y * m1) - Lm;
    mg.z = -0.5f * (sl.z + dv.z * m2) - Lm;
    mg.w = -0.5f * (sl.w + dv.w * m3) - Lm;
    *(float4*)(out_logits + idx) = lg;
    *(float4*)(out_margin + idx) = mg;
}

// ---------------- k5: scalar outputs ----------------
__global__ __launch_bounds__(256) void k5_scalars(
    const float* __restrict__ rowcd, const float* __restrict__ rowdet,
    float* __restrict__ out3, int B)
{
    __shared__ float redc[4], redd[4];
    int tid = threadIdx.x;
    float cd = 0.f, dt = 0.f;
    for (int b = tid; b < B; b += 256) { cd += rowcd[b]; dt += rowdet[b]; }
    #pragma unroll
    for (int off = 32; off > 0; off >>= 1) {
        cd += __shfl_xor(cd, off);
        dt += __shfl_xor(dt, off);
    }
    if ((tid & 63) == 0) { redc[tid >> 6] = cd; redd[tid >> 6] = dt; }
    __syncthreads();
    if (tid == 0) {
        cd = redc[0] + redc[1] + redc[2] + redc[3];
        dt = redd[0] + redd[1] + redd[2] + redd[3];
        float cdist = 0.5f * cd;
        float reg = 0.5f * (dt + 1e-8f);
        float likelihood = (cdist - reg) / (float)B;
        out3[0] = likelihood;
        out3[1] = cdist;
        out3[2] = reg;
    }
}

extern "C" void kernel_launch(void* const* d_in, const int* in_sizes, int n_in,
                              void* d_out, int out_size, void* d_ws, size_t ws_size,
                              hipStream_t stream) {
    const float* feat     = (const float*)d_in[0];
    const int*   label    = (const int*)d_in[1];
    const float* centers  = (const float*)d_in[2];
    const float* log_covs = (const float*)d_in[3];

    int B = in_sizes[1];
    int D = in_sizes[0] / B;          // 128
    int C = in_sizes[2] / D;          // 32000

    // workspace carve (all 16B aligned): ~37.2 MB total
    u16* Wh = (u16*)d_ws;
    u16* Wl = Wh + (size_t)C * 256;
    u16* Ah = Wl + (size_t)C * 256;
    u16* Al = Ah + (size_t)B * 256;
    float* sumc   = (float*)(Al + (size_t)B * 256);
    float* slog   = sumc + C;
    float* lse    = slog + C;
    float* lse_m  = lse + B;
    float* rowcd  = lse_m + B;
    float* rowdet = rowcd + B;

    float* out        = (float*)d_out;
    float* out_margin = out + (size_t)B * C;
    float* out3       = out + 2 * (size_t)B * C;

    k0_featprep<<<(B * D + 255) / 256, 256, 0, stream>>>(feat, Ah, Al, B * D);
    k1_classprep<<<C / 4, 256, 0, stream>>>(centers, log_covs, Wh, Wl, sumc, slog);
    k2_mfma<<<dim3(C / 128, B / 128), 256, 0, stream>>>(Ah, Al, Wh, Wl, sumc, out, C);
    k3_lse<<<B, 256, 0, stream>>>(out, slog, feat, centers, label,
                                  lse, lse_m, rowcd, rowdet, C);
    k4_final<<<dim3((C / 4 + 255) / 256, B), 256, 0, stream>>>(out, out_margin,
                                                               slog, label, lse,
                                                               lse_m, C);
    k5_scalars<<<1, 256, 0, stream>>>(rowcd, rowdet, out3, B);
}